// Round 1
// baseline (40996.310 us; speedup 1.0000x reference)
//
#include <hip/hip_runtime.h>
#include <math.h>

#define BATCH 2048
#define TT 256
#define DD 32
#define LL 16
#define AA 8
#define CC 64
#define HH 128
#define G3 384
#define BB 8
#define NBLK (BATCH/BB)

// ---- workspace layout (float offsets unless noted) ----
// bytes [0,64): 4 doubles: acc[0]=lp, acc[1]=kl, acc[2]=lr
#define WS_W1T_OFF   1024                    // post_w1T [128][80]
#define WS_W1TP_OFF  (WS_W1T_OFF + 10240)    // prior_w1T [128][16]
#define WS_Z0_OFF    (WS_W1TP_OFF + 2048)    // z0 [2048][16]
#define WS_CTX_OFF   65536                   // ctx [256][2048][64]
// total ws bytes needed: (65536 + 256*2048*64)*4 = 134,479,872

__device__ __forceinline__ float dot4(float4 a, float4 b){
  return a.x*b.x + a.y*b.y + a.z*b.z + a.w*b.w;
}
__device__ __forceinline__ float softplusf(float x){
  return fmaxf(x, 0.f) + log1pf(expf(-fabsf(x)));
}
__device__ __forceinline__ float sigmoidf(float x){
  return 1.f/(1.f + expf(-x));
}

// ---- init: transpose post_w1 (80x128 -> [n][k]) and prior_w1 (16x128 -> [n][k]) into ws
__global__ void init_kernel(const float* __restrict__ post_w1, const float* __restrict__ prior_w1,
                            float* __restrict__ ws){
  int tid = threadIdx.x;
  float* w1T = ws + WS_W1T_OFF;
  for (int idx = tid; idx < 80*128; idx += 256){ int k = idx >> 7, n = idx & 127; w1T[n*80 + k] = post_w1[idx]; }
  float* w1Tp = ws + WS_W1TP_OFF;
  for (int idx = tid; idx < 16*128; idx += 256){ int k = idx >> 7, n = idx & 127; w1Tp[n*16 + k] = prior_w1[idx]; }
}

// ---- GRU (backward over time) + ctx + z0 + KL(q(z0)||p(z0))
__global__ __launch_bounds__(256) void gru_kernel(
  const float* __restrict__ xs, const float* __restrict__ wih, const float* __restrict__ whh,
  const float* __restrict__ bih, const float* __restrict__ bhh,
  const float* __restrict__ enc_w, const float* __restrict__ enc_b,
  const float* __restrict__ qz0_w, const float* __restrict__ qz0_b,
  const float* __restrict__ eps_z0, const float* __restrict__ pz0_mean, const float* __restrict__ pz0_logstd,
  float* __restrict__ ws)
{
  __shared__ float h_lds[BB][HH];     // 4KB
  __shared__ float x_lds[BB][DD];     // 1KB
  __shared__ float encwT[CC][HH];     // 32KB
  __shared__ float scratch[2*G3*BB];  // 24KB : gi | gh, tail aliased at t==0
  float* gi = scratch;
  float* gh = scratch + G3*BB;

  const int tid = threadIdx.x;
  const int b0  = blockIdx.x * BB;
  double* acc   = (double*)ws;
  float* ws_z0  = ws + WS_Z0_OFF;
  float* ws_ctx = ws + WS_CTX_OFF;

  for (int idx = tid; idx < HH*CC; idx += 256){ int j = idx >> 6, c = idx & 63; encwT[c][j] = enc_w[idx]; }
  for (int idx = tid; idx < BB*HH; idx += 256) ((float*)h_lds)[idx] = 0.f;

  float bi0 = bih[tid], bh0 = bhh[tid], bi1 = 0.f, bh1 = 0.f;
  if (tid < G3 - 256){ bi1 = bih[tid+256]; bh1 = bhh[tid+256]; }
  double klacc = 0.0;
  __syncthreads();

  for (int t = TT-1; t >= 0; --t){
    // A: load x slice
    if (tid < BB*DD){ int r = tid >> 5, d = tid & 31; x_lds[r][d] = xs[((size_t)(b0+r)*TT + t)*DD + d]; }
    __syncthreads();
    // B: gi = x@wih.T + bih ; gh = h@whh.T + bhh  (thread-per-output-column)
    for (int c = 0; c < 2; ++c){
      int n = tid + c*256;
      if (n >= G3) break;
      float ai[BB], ah[BB];
      #pragma unroll
      for (int r = 0; r < BB; ++r){ ai[r] = 0.f; ah[r] = 0.f; }
      const float4* wi4 = (const float4*)(wih + (size_t)n*DD);
      #pragma unroll
      for (int kq = 0; kq < DD/4; ++kq){
        float4 w = wi4[kq];
        #pragma unroll
        for (int r = 0; r < BB; ++r){ float4 xv = *(const float4*)&x_lds[r][kq*4]; ai[r] += dot4(w, xv); }
      }
      const float4* wh4 = (const float4*)(whh + (size_t)n*HH);
      for (int kq = 0; kq < HH/4; ++kq){
        float4 w = wh4[kq];
        #pragma unroll
        for (int r = 0; r < BB; ++r){ float4 hv = *(const float4*)&h_lds[r][kq*4]; ah[r] += dot4(w, hv); }
      }
      float bi = c ? bi1 : bi0, bh = c ? bh1 : bh0;
      #pragma unroll
      for (int r = 0; r < BB; ++r){ gi[n*BB + r] = ai[r] + bi; gh[n*BB + r] = ah[r] + bh; }
    }
    __syncthreads();
    // C: gates + h update
    for (int idx = tid; idx < HH*BB; idx += 256){
      int j = idx & (HH-1); int r = idx >> 7;
      float rg = sigmoidf(gi[j*BB + r] + gh[j*BB + r]);
      float zg = sigmoidf(gi[(j+HH)*BB + r] + gh[(j+HH)*BB + r]);
      float ng = tanhf(gi[(j+2*HH)*BB + r] + rg*gh[(j+2*HH)*BB + r]);
      h_lds[r][j] = (1.f - zg)*ng + zg*h_lds[r][j];
    }
    __syncthreads();
    // D: ctx[t] = h@enc_w + enc_b
    float* ctx0 = scratch;   // alias (gi/gh dead after C)
    for (int idx = tid; idx < CC*BB; idx += 256){
      int c = idx & 63, r = idx >> 6;
      float s = enc_b[c];
      #pragma unroll
      for (int jq = 0; jq < HH/4; ++jq){
        float4 w  = *(const float4*)&encwT[c][jq*4];
        float4 hv = *(const float4*)&h_lds[r][jq*4];
        s += dot4(w, hv);
      }
      ws_ctx[((size_t)t*BATCH + b0 + r)*CC + c] = s;
      if (t == 0) ctx0[r*CC + c] = s;
    }
    __syncthreads();
    if (t == 0){
      float* qmb = scratch + 512;
      float* qlb = scratch + 640;
      { int m = tid & 31, r = tid >> 5;   // 256 = BB*32 exact
        float q = qz0_b[m];
        for (int c2 = 0; c2 < CC; ++c2) q += ctx0[r*CC + c2]*qz0_w[c2*32 + m];
        if (m < 16) qmb[r*16 + m] = q; else qlb[r*16 + (m-16)] = q;
      }
      __syncthreads();
      if (tid < BB*LL){
        int l = tid & 15, r = tid >> 4;
        float qm = qmb[r*16 + l], ql = qlb[r*16 + l];
        ws_z0[(size_t)(b0+r)*LL + l] = qm + expf(ql)*eps_z0[(size_t)(b0+r)*LL + l];
        float pm = pz0_mean[l], pl = pz0_logstd[l];
        float d  = qm - pm;
        klacc = (double)(pl - ql + (expf(2.f*ql) + d*d)/(2.f*expf(2.f*pl)) - 0.5f);
      }
    }
    __syncthreads();
  }
  double* redb = (double*)(scratch + 1024);
  redb[tid] = klacc;
  __syncthreads();
  if (tid == 0){ double s = 0; for (int i = 0; i < 256; ++i) s += redb[i]; atomicAdd(&acc[1], s); }
}

// ---- SDE scan + fused projection/likelihood ----
// LDS float offsets
#define S_W2P  0
#define S_W2R  16384
#define S_ZIN  32768   /* [8][80]: cols 0..15 = z (persistent), 16..79 = ctx */
#define S_HDD  33408   /* [8][128] */
#define S_MAT  34432   /* [8][128] */
#define S_PSUM 33408   /* [16][16][8] aliases HDD+MAT */
#define S_FB   35456
#define S_HB   35584
#define S_G0   35712
#define S_Z2   35840   /* z+g0*dw, then u^2 */
#define S_DWV  35968
#define S_DXV  36096
#define S_XSL  36160
#define S_H1   36416
#define S_H2   36672
#define S_RED  37184   /* 256 doubles */
#define S_TOTAL 37696

__global__ __launch_bounds__(256) void sde_kernel(
  const float* __restrict__ xs, const float* __restrict__ ts, const float* __restrict__ act, const float* __restrict__ dW,
  const float* __restrict__ prior_b1, const float* __restrict__ prior_w2, const float* __restrict__ prior_b2,
  const float* __restrict__ post_b1,  const float* __restrict__ post_w2,  const float* __restrict__ post_b2,
  const float* __restrict__ g_w1, const float* __restrict__ g_b1, const float* __restrict__ g_w2, const float* __restrict__ g_b2,
  const float* __restrict__ pw1, const float* __restrict__ pb1, const float* __restrict__ pw2, const float* __restrict__ pb2,
  const float* __restrict__ pw3, const float* __restrict__ pb3,
  float* __restrict__ ws)
{
  extern __shared__ __align__(16) float sm[];
  const int tid = threadIdx.x;
  const int b0  = blockIdx.x * BB;
  double* acc = (double*)ws;
  const float* w1T    = ws + WS_W1T_OFF;
  const float* w1Tp   = ws + WS_W1TP_OFF;
  const float* ws_z0  = ws + WS_Z0_OFF;
  const float* ws_ctx = ws + WS_CTX_OFF;

  for (int idx = tid; idx < HH*HH; idx += 256){
    int h = idx >> 7, j = idx & 127;
    sm[S_W2P + j*HH + h] = post_w2[idx];
    sm[S_W2R + j*HH + h] = prior_w2[idx];
  }
  if (tid < BB*LL){ int r = tid >> 4, l = tid & 15; sm[S_ZIN + r*80 + l] = ws_z0[(size_t)(b0+r)*LL + l]; }
  double lpacc = 0.0, lracc = 0.0;
  __syncthreads();

  for (int t = 0; t < TT; ++t){
    // xs slice for time t
    { int r = tid >> 5, d = tid & 31; sm[S_XSL + r*DD + d] = xs[((size_t)(b0+r)*TT + t)*DD + d]; }
    __syncthreads();
    // ---- projection of current z ----
    { int r = tid >> 5, c = tid & 31;
      float s = pb1[c];
      #pragma unroll
      for (int l = 0; l < LL; ++l) s += sm[S_ZIN + r*80 + l]*pw1[l*32 + c];
      sm[S_H1 + r*32 + c] = tanhf(s);
    }
    __syncthreads();
    for (int idx = tid; idx < BB*CC; idx += 256){
      int r = idx >> 6, c = idx & 63;
      float s = pb2[c];
      #pragma unroll
      for (int k2 = 0; k2 < 32; ++k2) s += sm[S_H1 + r*32 + k2]*pw2[k2*64 + c];
      sm[S_H2 + r*CC + c] = tanhf(s);
    }
    __syncthreads();
    { int r = tid >> 5, d = tid & 31;
      float s = pb3[d];
      #pragma unroll
      for (int k2 = 0; k2 < CC; ++k2) s += sm[S_H2 + r*CC + k2]*pw3[k2*32 + d];
      float diff = (sm[S_XSL + r*DD + d] - s)*10.f;
      lpacc += (double)(-0.5f*diff*diff + 1.3836465597893728f);  // -LOG_NOISE_STD - HALF_LOG2PI
    }
    if (t == TT-1) break;

    // ---- SDE step t -> t+1 ----
    float dtk = ts[t+1] - ts[t];
    float sqd = sqrtf(dtk);
    for (int idx = tid; idx < BB*CC; idx += 256){
      int r = idx >> 6, c = idx & 63;
      sm[S_ZIN + r*80 + 16 + c] = ws_ctx[((size_t)(t+1)*BATCH + b0 + r)*CC + c];
    }
    if (tid < BB*LL){ int r = tid >> 4, l = tid & 15;
      sm[S_DWV + r*16 + l] = dW[((size_t)t*BATCH + (b0+r))*LL + l]*sqd;
    }
    if (tid < BB*AA){ int r = tid >> 3, a = tid & 7;
      size_t base = ((size_t)(b0+r)*TT + t)*AA + a;
      sm[S_DXV + r*8 + a] = (act[base + AA] - act[base])/dtk;
    }
    __syncthreads();
    // P1: hdd_post = tanh([z|ctx]@post_w1 + b1)
    { int n = tid >> 1, g = tid & 1; int rb = g*4;
      float a0 = post_b1[n]; float a1 = a0, a2 = a0, a3 = a0;
      const float4* w4 = (const float4*)(w1T + n*80);
      for (int kq = 0; kq < 20; ++kq){
        float4 w = w4[kq];
        float4 z0v = *(const float4*)&sm[S_ZIN + (rb+0)*80 + kq*4];
        float4 z1v = *(const float4*)&sm[S_ZIN + (rb+1)*80 + kq*4];
        float4 z2v = *(const float4*)&sm[S_ZIN + (rb+2)*80 + kq*4];
        float4 z3v = *(const float4*)&sm[S_ZIN + (rb+3)*80 + kq*4];
        a0 += dot4(w, z0v); a1 += dot4(w, z1v); a2 += dot4(w, z2v); a3 += dot4(w, z3v);
      }
      sm[S_HDD + (rb+0)*HH + n] = tanhf(a0);
      sm[S_HDD + (rb+1)*HH + n] = tanhf(a1);
      sm[S_HDD + (rb+2)*HH + n] = tanhf(a2);
      sm[S_HDD + (rb+3)*HH + n] = tanhf(a3);
    }
    __syncthreads();
    // P2: mat_post = hdd@post_w2 + b2
    { int j = tid >> 1, g = tid & 1; int rb = g*4;
      float m0 = post_b2[j]; float m1 = m0, m2 = m0, m3 = m0;
      for (int kq = 0; kq < 32; ++kq){
        float4 w  = *(const float4*)&sm[S_W2P + j*HH + kq*4];
        float4 h0 = *(const float4*)&sm[S_HDD + (rb+0)*HH + kq*4];
        float4 h1 = *(const float4*)&sm[S_HDD + (rb+1)*HH + kq*4];
        float4 h2 = *(const float4*)&sm[S_HDD + (rb+2)*HH + kq*4];
        float4 h3 = *(const float4*)&sm[S_HDD + (rb+3)*HH + kq*4];
        m0 += dot4(w, h0); m1 += dot4(w, h1); m2 += dot4(w, h2); m3 += dot4(w, h3);
      }
      sm[S_MAT + (rb+0)*HH + j] = m0;
      sm[S_MAT + (rb+1)*HH + j] = m1;
      sm[S_MAT + (rb+2)*HH + j] = m2;
      sm[S_MAT + (rb+3)*HH + j] = m3;
    }
    __syncthreads();
    // P2b: f = einsum(mat, dxdt)   ||   P3: hdd_prior = tanh(z@prior_w1 + b1)  (disjoint LDS)
    if (tid < BB*LL){ int r = tid >> 4, l = tid & 15;
      float f = 0.f;
      #pragma unroll
      for (int a2 = 0; a2 < AA; ++a2) f += sm[S_MAT + r*HH + l*8 + a2]*sm[S_DXV + r*8 + a2];
      sm[S_FB + r*16 + l] = f;
    }
    __syncthreads();
    { int n = tid >> 1, g = tid & 1; int rb = g*4;
      float a0 = prior_b1[n]; float a1 = a0, a2 = a0, a3 = a0;
      const float4* w4 = (const float4*)(w1Tp + n*16);
      #pragma unroll
      for (int kq = 0; kq < 4; ++kq){
        float4 w = w4[kq];
        float4 z0v = *(const float4*)&sm[S_ZIN + (rb+0)*80 + kq*4];
        float4 z1v = *(const float4*)&sm[S_ZIN + (rb+1)*80 + kq*4];
        float4 z2v = *(const float4*)&sm[S_ZIN + (rb+2)*80 + kq*4];
        float4 z3v = *(const float4*)&sm[S_ZIN + (rb+3)*80 + kq*4];
        a0 += dot4(w, z0v); a1 += dot4(w, z1v); a2 += dot4(w, z2v); a3 += dot4(w, z3v);
      }
      sm[S_HDD + (rb+0)*HH + n] = tanhf(a0);
      sm[S_HDD + (rb+1)*HH + n] = tanhf(a1);
      sm[S_HDD + (rb+2)*HH + n] = tanhf(a2);
      sm[S_HDD + (rb+3)*HH + n] = tanhf(a3);
    }
    __syncthreads();
    // P4: mat_prior
    { int j = tid >> 1, g = tid & 1; int rb = g*4;
      float m0 = prior_b2[j]; float m1 = m0, m2 = m0, m3 = m0;
      for (int kq = 0; kq < 32; ++kq){
        float4 w  = *(const float4*)&sm[S_W2R + j*HH + kq*4];
        float4 h0 = *(const float4*)&sm[S_HDD + (rb+0)*HH + kq*4];
        float4 h1 = *(const float4*)&sm[S_HDD + (rb+1)*HH + kq*4];
        float4 h2 = *(const float4*)&sm[S_HDD + (rb+2)*HH + kq*4];
        float4 h3 = *(const float4*)&sm[S_HDD + (rb+3)*HH + kq*4];
        m0 += dot4(w, h0); m1 += dot4(w, h1); m2 += dot4(w, h2); m3 += dot4(w, h3);
      }
      sm[S_MAT + (rb+0)*HH + j] = m0;
      sm[S_MAT + (rb+1)*HH + j] = m1;
      sm[S_MAT + (rb+2)*HH + j] = m2;
      sm[S_MAT + (rb+3)*HH + j] = m3;
    }
    __syncthreads();
    // P4b: h_val
    if (tid < BB*LL){ int r = tid >> 4, l = tid & 15;
      float h = 0.f;
      #pragma unroll
      for (int a2 = 0; a2 < AA; ++a2) h += sm[S_MAT + r*HH + l*8 + a2]*sm[S_DXV + r*8 + a2];
      sm[S_HB + r*16 + l] = h;
    }
    __syncthreads();
    // P5/P6: diffusion g0, g1 (two passes), then state update
    for (int pass = 0; pass < 2; ++pass){
      { int l = tid >> 4, i = tid & 15;
        const float4 w1a = *(const float4*)&g_w1[l*HH + i*8];
        const float4 w1b = *(const float4*)&g_w1[l*HH + i*8 + 4];
        const float4 b1a = *(const float4*)&g_b1[l*HH + i*8];
        const float4 b1b = *(const float4*)&g_b1[l*HH + i*8 + 4];
        const float4 w2a = *(const float4*)&g_w2[l*HH + i*8];
        const float4 w2b = *(const float4*)&g_w2[l*HH + i*8 + 4];
        #pragma unroll
        for (int r = 0; r < BB; ++r){
          float z = pass ? sm[S_Z2 + r*16 + l] : sm[S_ZIN + r*80 + l];
          float s = softplusf(z*w1a.x + b1a.x)*w2a.x + softplusf(z*w1a.y + b1a.y)*w2a.y
                  + softplusf(z*w1a.z + b1a.z)*w2a.z + softplusf(z*w1a.w + b1a.w)*w2a.w
                  + softplusf(z*w1b.x + b1b.x)*w2b.x + softplusf(z*w1b.y + b1b.y)*w2b.y
                  + softplusf(z*w1b.z + b1b.z)*w2b.z + softplusf(z*w1b.w + b1b.w)*w2b.w;
          sm[S_PSUM + (l*16 + i)*8 + r] = s;
        }
      }
      __syncthreads();
      if (pass == 0){
        if (tid < BB*LL){ int r = tid >> 4, l = tid & 15;
          float s = g_b2[l];
          #pragma unroll
          for (int i2 = 0; i2 < 16; ++i2) s += sm[S_PSUM + (l*16 + i2)*8 + r];
          float g0 = sigmoidf(s);
          sm[S_G0 + r*16 + l] = g0;
          sm[S_Z2 + r*16 + l] = sm[S_ZIN + r*80 + l] + g0*sm[S_DWV + r*16 + l];
        }
      } else {
        if (tid < BB*LL){ int r = tid >> 4, l = tid & 15;
          float s = g_b2[l];
          #pragma unroll
          for (int i2 = 0; i2 < 16; ++i2) s += sm[S_PSUM + (l*16 + i2)*8 + r];
          float g1  = sigmoidf(s);
          float g0  = sm[S_G0 + r*16 + l];
          float fv  = sm[S_FB + r*16 + l];
          float hv  = sm[S_HB + r*16 + l];
          float dwv = sm[S_DWV + r*16 + l];
          float zc  = sm[S_ZIN + r*80 + l];
          float zn  = zc + fv*dtk + 0.5f*(g0 + g1)*dwv;
          float u   = (fv - hv)/g0;
          sm[S_Z2 + r*16 + l] = u*u;
          sm[S_ZIN + r*80 + l] = zn;
        }
      }
      __syncthreads();
    }
    // lr accumulation (per row)
    if (tid < BB){
      float s2 = 0.f;
      #pragma unroll
      for (int l = 0; l < LL; ++l) s2 += sm[S_Z2 + tid*16 + l];
      lracc += (double)(0.5f*s2*dtk);
    }
    __syncthreads();
  }

  // reductions
  double* redb = (double*)&sm[S_RED];
  redb[tid] = lpacc;
  __syncthreads();
  if (tid == 0){ double s = 0; for (int i = 0; i < 256; ++i) s += redb[i]; atomicAdd(&acc[0], s); }
  __syncthreads();
  redb[tid] = (tid < BB) ? lracc : 0.0;
  __syncthreads();
  if (tid == 0){ double s = 0; for (int i = 0; i < 256; ++i) s += redb[i]; atomicAdd(&acc[2], s); }
}

__global__ void fin_kernel(const float* __restrict__ ws, float* __restrict__ out){
  const double* acc = (const double*)ws;
  out[0] = (float)(acc[0]/2048.0);
  out[1] = (float)(acc[1]/16.0 + acc[2]/255.0);
}

extern "C" void kernel_launch(void* const* d_in, const int* in_sizes, int n_in,
                              void* d_out, int out_size, void* d_ws, size_t ws_size,
                              hipStream_t stream)
{
  const float* xs        = (const float*)d_in[0];
  const float* ts        = (const float*)d_in[1];
  const float* act       = (const float*)d_in[2];
  const float* eps_z0    = (const float*)d_in[3];
  const float* dW        = (const float*)d_in[4];
  const float* gru_wih   = (const float*)d_in[5];
  const float* gru_whh   = (const float*)d_in[6];
  const float* gru_bih   = (const float*)d_in[7];
  const float* gru_bhh   = (const float*)d_in[8];
  const float* enc_w     = (const float*)d_in[9];
  const float* enc_b     = (const float*)d_in[10];
  const float* qz0_w     = (const float*)d_in[11];
  const float* qz0_b     = (const float*)d_in[12];
  const float* prior_w1  = (const float*)d_in[13];
  const float* prior_b1  = (const float*)d_in[14];
  const float* prior_w2  = (const float*)d_in[15];
  const float* prior_b2  = (const float*)d_in[16];
  const float* post_w1   = (const float*)d_in[17];
  const float* post_b1   = (const float*)d_in[18];
  const float* post_w2   = (const float*)d_in[19];
  const float* post_b2   = (const float*)d_in[20];
  const float* g_w1      = (const float*)d_in[21];
  const float* g_b1      = (const float*)d_in[22];
  const float* g_w2      = (const float*)d_in[23];
  const float* g_b2      = (const float*)d_in[24];
  const float* pw1       = (const float*)d_in[25];
  const float* pb1       = (const float*)d_in[26];
  const float* pw2       = (const float*)d_in[27];
  const float* pb2       = (const float*)d_in[28];
  const float* pw3       = (const float*)d_in[29];
  const float* pb3       = (const float*)d_in[30];
  const float* pz0_mean  = (const float*)d_in[31];
  const float* pz0_logstd= (const float*)d_in[32];
  float* ws = (float*)d_ws;

  hipMemsetAsync(d_ws, 0, 64, stream);
  init_kernel<<<1, 256, 0, stream>>>(post_w1, prior_w1, ws);
  gru_kernel<<<NBLK, 256, 0, stream>>>(xs, gru_wih, gru_whh, gru_bih, gru_bhh,
                                       enc_w, enc_b, qz0_w, qz0_b, eps_z0, pz0_mean, pz0_logstd, ws);
  int sde_lds = S_TOTAL*4;
  hipFuncSetAttribute(reinterpret_cast<const void*>(sde_kernel),
                      hipFuncAttributeMaxDynamicSharedMemorySize, sde_lds);
  sde_kernel<<<NBLK, 256, sde_lds, stream>>>(xs, ts, act, dW,
                                             prior_b1, prior_w2, prior_b2,
                                             post_b1, post_w2, post_b2,
                                             g_w1, g_b1, g_w2, g_b2,
                                             pw1, pb1, pw2, pb2, pw3, pb3, ws);
  fin_kernel<<<1, 1, 0, stream>>>(ws, (float*)d_out);
}

// Round 3
// 13501.009 us; speedup vs baseline: 3.0365x; 3.0365x over previous
//
#include <hip/hip_runtime.h>
#include <math.h>

#define BATCH 2048
#define TT 256
#define DD 32
#define LL 16
#define AA 8
#define CC 64
#define HH 128
#define G3 384
#define BB 8
#define NBLK (BATCH/BB)

// ---- workspace layout (float offsets) ----
// bytes [0,64): doubles acc[0]=lp, acc[1]=kl, acc[2]=lr
#define WS_W1T_OFF   1024                    // post_w1T [128][80]
#define WS_W1TP_OFF  11264                   // prior_w1T [128][16]
#define WS_ZS_OFF    16384                   // zs [256][2048][16]
#define WS_CTX_OFF   (WS_ZS_OFF + TT*BATCH*LL)  // ctx [256][2048][64]
// total floats = 16384 + 8388608 + 33554432 = 41959424  (~160MB)

__device__ __forceinline__ float dot4(float4 a, float4 b){
  return a.x*b.x + a.y*b.y + a.z*b.z + a.w*b.w;
}
__device__ __forceinline__ float softplusf(float x){
  return fmaxf(x, 0.f) + log1pf(expf(-fabsf(x)));
}
__device__ __forceinline__ float sigmoidf(float x){
  return 1.f/(1.f + expf(-x));
}

// ---- init: transpose post_w1 (80x128) and prior_w1 (16x128) into ws
__global__ void init_kernel(const float* __restrict__ post_w1, const float* __restrict__ prior_w1,
                            float* __restrict__ ws){
  int tid = threadIdx.x;
  float* w1T = ws + WS_W1T_OFF;
  for (int idx = tid; idx < 80*128; idx += 256){ int k = idx >> 7, n = idx & 127; w1T[n*80 + k] = post_w1[idx]; }
  float* w1Tp = ws + WS_W1TP_OFF;
  for (int idx = tid; idx < 16*128; idx += 256){ int k = idx >> 7, n = idx & 127; w1Tp[n*16 + k] = prior_w1[idx]; }
}

// ---- GRU (backward over time) + ctx + z0(->zs[0]) + KL ----
__global__ __launch_bounds__(384) void gru_kernel(
  const float* __restrict__ xs, const float* __restrict__ wih, const float* __restrict__ whh,
  const float* __restrict__ bih, const float* __restrict__ bhh,
  const float* __restrict__ enc_w, const float* __restrict__ enc_b,
  const float* __restrict__ qz0_w, const float* __restrict__ qz0_b,
  const float* __restrict__ eps_z0, const float* __restrict__ pz0_mean, const float* __restrict__ pz0_logstd,
  float* __restrict__ ws)
{
  __shared__ float h_lds[BB][HH];      // 4KB
  __shared__ float x_lds[BB][DD];      // 1KB
  __shared__ float encwT[CC*HH];       // 32KB, swizzled [c][j ^ ((c&15)<<2)]
  __shared__ float scratch[2*G3*9];    // 27KB: gi | gh at stride 9
  float* gi = scratch;
  float* gh = scratch + G3*9;

  const int tid = threadIdx.x;
  const int b0  = blockIdx.x * BB;
  double* acc   = (double*)ws;
  float* ws_zs  = ws + WS_ZS_OFF;
  float* ws_ctx = ws + WS_CTX_OFF;

  for (int idx = tid; idx < HH*CC; idx += 384){
    int j = idx >> 6, c = idx & 63;
    encwT[c*HH + (j ^ ((c&15)<<2))] = enc_w[idx];
  }
  for (int idx = tid; idx < BB*HH; idx += 384) ((float*)h_lds)[idx] = 0.f;

  const float bi0 = bih[tid], bh0 = bhh[tid];   // 384 threads == G3
  double klacc = 0.0;
  __syncthreads();

  for (int t = TT-1; t >= 0; --t){
    if (tid < BB*DD){ int r = tid >> 5, d = tid & 31; x_lds[r][d] = xs[((size_t)(b0+r)*TT + t)*DD + d]; }
    __syncthreads();
    // B: gi = x@wih.T + bih ; gh = h@whh.T + bhh  (thread n = output column)
    { const int n = tid;
      float ai[BB], ah[BB];
      #pragma unroll
      for (int r = 0; r < BB; ++r){ ai[r] = 0.f; ah[r] = 0.f; }
      const float4* wi4 = (const float4*)(wih + (size_t)n*DD);
      #pragma unroll 2
      for (int kq = 0; kq < DD/4; ++kq){
        float4 w = wi4[kq];
        #pragma unroll
        for (int r = 0; r < BB; ++r){ float4 xv = *(const float4*)&x_lds[r][kq*4]; ai[r] += dot4(w, xv); }
      }
      const float4* wh4 = (const float4*)(whh + (size_t)n*HH);
      #pragma unroll 2
      for (int kq = 0; kq < HH/4; ++kq){
        float4 w = wh4[kq];
        #pragma unroll
        for (int r = 0; r < BB; ++r){ float4 hv = *(const float4*)&h_lds[r][kq*4]; ah[r] += dot4(w, hv); }
      }
      #pragma unroll
      for (int r = 0; r < BB; ++r){ gi[n*9 + r] = ai[r] + bi0; gh[n*9 + r] = ah[r] + bh0; }
    }
    __syncthreads();
    // C: gates + h update
    for (int idx = tid; idx < HH*BB; idx += 384){
      int j = idx & (HH-1); int r = idx >> 7;
      float rg = sigmoidf(gi[j*9 + r] + gh[j*9 + r]);
      float zg = sigmoidf(gi[(j+HH)*9 + r] + gh[(j+HH)*9 + r]);
      float ng = tanhf(gi[(j+2*HH)*9 + r] + rg*gh[(j+2*HH)*9 + r]);
      h_lds[r][j] = (1.f - zg)*ng + zg*h_lds[r][j];
    }
    __syncthreads();
    // D: ctx[t] = h@enc_w + enc_b
    float* ctx0 = scratch;   // alias (gi dead after C)
    for (int idx = tid; idx < CC*BB; idx += 384){
      int c = idx & 63, r = idx >> 6;
      float s = enc_b[c];
      #pragma unroll 4
      for (int jq = 0; jq < HH/4; ++jq){
        float4 w  = *(const float4*)&encwT[c*HH + ((jq*4) ^ ((c&15)<<2))];
        float4 hv = *(const float4*)&h_lds[r][jq*4];
        s += dot4(w, hv);
      }
      ws_ctx[((size_t)t*BATCH + b0 + r)*CC + c] = s;
      if (t == 0) ctx0[r*CC + c] = s;
    }
    __syncthreads();
    if (t == 0){
      float* qmb = scratch + 512;
      float* qlb = scratch + 640;
      if (tid < 256){ int m = tid & 31, r = tid >> 5;
        float q = qz0_b[m];
        for (int c2 = 0; c2 < CC; ++c2) q += ctx0[r*CC + c2]*qz0_w[c2*32 + m];
        if (m < 16) qmb[r*16 + m] = q; else qlb[r*16 + (m-16)] = q;
      }
      __syncthreads();
      if (tid < BB*LL){
        int l = tid & 15, r = tid >> 4;
        float qm = qmb[r*16 + l], ql = qlb[r*16 + l];
        ws_zs[(size_t)(b0+r)*LL + l] = qm + expf(ql)*eps_z0[(size_t)(b0+r)*LL + l];
        float pm = pz0_mean[l], pl = pz0_logstd[l];
        float d  = qm - pm;
        klacc = (double)(pl - ql + (expf(2.f*ql) + d*d)/(2.f*expf(2.f*pl)) - 0.5f);
      }
    }
    __syncthreads();
  }
  double* redb = (double*)(scratch + 1024);
  redb[tid] = klacc;
  __syncthreads();
  if (tid == 0){ double s = 0; for (int i = 0; i < 384; ++i) s += redb[i]; atomicAdd(&acc[1], s); }
}

// ---- SDE scan (projection moved out) ----
// LDS float offsets
#define S_W2P  0       /* [128][128] swizzled */
#define S_W2R  16384
#define S_ZIN  32768   /* [8][80]: 0..15 z, 16..79 ctx(t+1) */
#define S_HDP  33408   /* [8][128] post hdd; PSUM alias */
#define S_HDR  34432   /* [8][128] prior hdd */
#define S_PSUM S_HDP   /* [16] rows stride 65: l*65 + k*8 + r (k<8) -> 1039 floats */
#define S_MATP 35456   /* [8][128]; RED alias (512 doubles) */
#define S_MATR 36480   /* [8][128] */
#define S_Z2   37504   /* [8][16] */
#define S_DXV  37632   /* [8][8] */
#define S_TOTAL 37696  /* floats -> 150784 bytes */

__global__ __launch_bounds__(512) void sde_kernel(
  const float* __restrict__ ts, const float* __restrict__ act, const float* __restrict__ dW,
  const float* __restrict__ prior_b1, const float* __restrict__ prior_w2, const float* __restrict__ prior_b2,
  const float* __restrict__ post_b1,  const float* __restrict__ post_w2,  const float* __restrict__ post_b2,
  const float* __restrict__ g_w1, const float* __restrict__ g_b1, const float* __restrict__ g_w2, const float* __restrict__ g_b2,
  float* __restrict__ ws)
{
  extern __shared__ __align__(16) float sm[];
  const int tid = threadIdx.x;
  const int b0  = blockIdx.x * BB;
  double* acc = (double*)ws;
  const float* w1T    = ws + WS_W1T_OFF;
  const float* w1Tp   = ws + WS_W1TP_OFF;
  float*       ws_zs  = ws + WS_ZS_OFF;
  const float* ws_ctx = ws + WS_CTX_OFF;

  // stage w2 matrices, XOR-swizzled: [j][h ^ ((j&15)<<2)]
  for (int idx = tid; idx < HH*HH; idx += 512){
    int h = idx >> 7, j = idx & 127;
    int d = j*HH + (h ^ ((j&15)<<2));
    sm[S_W2P + d] = post_w2[idx];
    sm[S_W2R + d] = prior_w2[idx];
  }
  float dwraw = 0.f;               // dW for current step (tid<128: (r,l))
  float g0_reg = 0.f, fv_reg = 0.f, hv_reg = 0.f;
  double lracc = 0.0;
  if (tid < BB*LL){
    int r = tid >> 4, l = tid & 15;
    sm[S_ZIN + r*80 + l] = ws_zs[(size_t)(b0+r)*LL + l];
    dwraw = dW[(size_t)(b0+r)*LL + l];            // t=0
  } else {
    for (int k = tid-128; k < BB*CC; k += 384){   // ctx[1]
      int r = k >> 6, c = k & 63;
      sm[S_ZIN + r*80 + 16 + c] = ws_ctx[((size_t)1*BATCH + b0 + r)*CC + c];
    }
    if (tid < 192){ int k = tid-128; int r = k >> 3, a = k & 7;
      float dt0 = ts[1] - ts[0];
      size_t base = ((size_t)(b0+r)*TT)*AA + a;
      sm[S_DXV + r*8 + a] = (act[base + AA] - act[base])/dt0;
    }
  }
  __syncthreads();

  for (int t = 0; t < TT-1; ++t){
    const float dtk = ts[t+1] - ts[t];
    const float sqd = sqrtf(dtk);

    // A: hdd_post = tanh([z|ctx]@post_w1+b1); hdd_prior = tanh(z@prior_w1+b1)
    { const int n = tid >> 2, q = tid & 3; const int r0 = q, r1 = q + 4;
      const float4* w4 = (const float4*)(w1T + n*80);
      float a0 = post_b1[n]; float a1 = a0;
      #pragma unroll 5
      for (int kq = 0; kq < 20; ++kq){
        float4 w = w4[kq];
        float4 z0v = *(const float4*)&sm[S_ZIN + r0*80 + kq*4];
        float4 z1v = *(const float4*)&sm[S_ZIN + r1*80 + kq*4];
        a0 += dot4(w, z0v); a1 += dot4(w, z1v);
      }
      sm[S_HDP + r0*HH + n] = tanhf(a0);
      sm[S_HDP + r1*HH + n] = tanhf(a1);
      const float4* wp4 = (const float4*)(w1Tp + n*16);
      float c0 = prior_b1[n]; float c1 = c0;
      #pragma unroll
      for (int kq = 0; kq < 4; ++kq){
        float4 w = wp4[kq];
        float4 z0v = *(const float4*)&sm[S_ZIN + r0*80 + kq*4];
        float4 z1v = *(const float4*)&sm[S_ZIN + r1*80 + kq*4];
        c0 += dot4(w, z0v); c1 += dot4(w, z1v);
      }
      sm[S_HDR + r0*HH + n] = tanhf(c0);
      sm[S_HDR + r1*HH + n] = tanhf(c1);
    }
    __syncthreads();
    // B: mat_post, mat_prior
    { const int j = tid >> 2, q = tid & 3; const int r0 = q, r1 = q + 4;
      float mp0 = post_b2[j];  float mp1 = mp0;
      float mr0 = prior_b2[j]; float mr1 = mr0;
      #pragma unroll 2
      for (int kq = 0; kq < 32; ++kq){
        int wo = (kq*4) ^ ((j&15)<<2);
        float4 wp = *(const float4*)&sm[S_W2P + j*HH + wo];
        float4 wr = *(const float4*)&sm[S_W2R + j*HH + wo];
        float4 p0 = *(const float4*)&sm[S_HDP + r0*HH + kq*4];
        float4 p1 = *(const float4*)&sm[S_HDP + r1*HH + kq*4];
        float4 q0 = *(const float4*)&sm[S_HDR + r0*HH + kq*4];
        float4 q1 = *(const float4*)&sm[S_HDR + r1*HH + kq*4];
        mp0 += dot4(wp, p0); mp1 += dot4(wp, p1);
        mr0 += dot4(wr, q0); mr1 += dot4(wr, q1);
      }
      sm[S_MATP + r0*HH + j] = mp0; sm[S_MATP + r1*HH + j] = mp1;
      sm[S_MATR + r0*HH + j] = mr0; sm[S_MATR + r1*HH + j] = mr1;
    }
    __syncthreads();
    // C: g0 partial sums (all threads) + f/h einsums (tid<128, into regs)
    { const int l = tid >> 5, i = tid & 31;
      const float4 w1v = *(const float4*)&g_w1[l*HH + i*4];
      const float4 b1v = *(const float4*)&g_b1[l*HH + i*4];
      const float4 w2v = *(const float4*)&g_w2[l*HH + i*4];
      #pragma unroll
      for (int r = 0; r < BB; ++r){
        float z = sm[S_ZIN + r*80 + l];
        float s = softplusf(z*w1v.x + b1v.x)*w2v.x + softplusf(z*w1v.y + b1v.y)*w2v.y
                + softplusf(z*w1v.z + b1v.z)*w2v.z + softplusf(z*w1v.w + b1v.w)*w2v.w;
        s += __shfl_xor(s, 1); s += __shfl_xor(s, 2);
        if ((i & 3) == 0) sm[S_PSUM + l*65 + (i>>2)*8 + r] = s;
      }
    }
    if (tid < BB*LL){
      int r = tid >> 4, l = tid & 15;
      float f = 0.f, h = 0.f;
      #pragma unroll
      for (int a2 = 0; a2 < AA; ++a2){
        float dx = sm[S_DXV + r*8 + a2];
        f += sm[S_MATP + r*HH + l*8 + a2]*dx;
        h += sm[S_MATR + r*HH + l*8 + a2]*dx;
      }
      fv_reg = f; hv_reg = h;
    }
    __syncthreads();
    // D: g0 reduce + z2 = z + g0*dw
    if (tid < BB*LL){
      int r = tid >> 4, l = tid & 15;
      float s = g_b2[l];
      #pragma unroll
      for (int k = 0; k < 8; ++k) s += sm[S_PSUM + l*65 + k*8 + r];
      g0_reg = sigmoidf(s);
      float dwv = dwraw*sqd;
      sm[S_Z2 + r*16 + l] = sm[S_ZIN + r*80 + l] + g0_reg*dwv;
    }
    __syncthreads();
    // E: g1 partial sums
    { const int l = tid >> 5, i = tid & 31;
      const float4 w1v = *(const float4*)&g_w1[l*HH + i*4];
      const float4 b1v = *(const float4*)&g_b1[l*HH + i*4];
      const float4 w2v = *(const float4*)&g_w2[l*HH + i*4];
      #pragma unroll
      for (int r = 0; r < BB; ++r){
        float z = sm[S_Z2 + r*16 + l];
        float s = softplusf(z*w1v.x + b1v.x)*w2v.x + softplusf(z*w1v.y + b1v.y)*w2v.y
                + softplusf(z*w1v.z + b1v.z)*w2v.z + softplusf(z*w1v.w + b1v.w)*w2v.w;
        s += __shfl_xor(s, 1); s += __shfl_xor(s, 2);
        if ((i & 3) == 0) sm[S_PSUM + l*65 + (i>>2)*8 + r] = s;
      }
    }
    __syncthreads();
    // F: g1 reduce, state update, lr accumulate, store zs  || L: prefetch next step
    if (tid < BB*LL){
      int r = tid >> 4, l = tid & 15;
      float s = g_b2[l];
      #pragma unroll
      for (int k = 0; k < 8; ++k) s += sm[S_PSUM + l*65 + k*8 + r];
      float g1  = sigmoidf(s);
      float dwv = dwraw*sqd;
      float zc  = sm[S_ZIN + r*80 + l];
      float zn  = zc + fv_reg*dtk + 0.5f*(g0_reg + g1)*dwv;
      float u   = (fv_reg - hv_reg)/g0_reg;
      lracc += (double)(0.5f*(u*u)*dtk);
      sm[S_ZIN + r*80 + l] = zn;
      ws_zs[((size_t)(t+1)*BATCH + b0 + r)*LL + l] = zn;
      if (t < TT-2) dwraw = dW[((size_t)(t+1)*BATCH + (b0+r))*LL + l];
    } else if (t < TT-2){
      for (int k = tid-128; k < BB*CC; k += 384){
        int r = k >> 6, c = k & 63;
        sm[S_ZIN + r*80 + 16 + c] = ws_ctx[((size_t)(t+2)*BATCH + b0 + r)*CC + c];
      }
      if (tid < 192){ int k = tid-128; int r = k >> 3, a = k & 7;
        float dtn = ts[t+2] - ts[t+1];
        size_t base = ((size_t)(b0+r)*TT + (t+1))*AA + a;
        sm[S_DXV + r*8 + a] = (act[base + AA] - act[base])/dtn;
      }
    }
    __syncthreads();
  }

  // lr reduction (alias MATP region for 512 doubles)
  double* redb = (double*)&sm[S_MATP];
  redb[tid] = lracc;
  __syncthreads();
  if (tid == 0){ double s = 0; for (int i = 0; i < 512; ++i) s += redb[i]; atomicAdd(&acc[2], s); }
}

// ---- fully parallel projection + log-likelihood over all (t,b) ----
__global__ __launch_bounds__(256) void proj_kernel(
  const float* __restrict__ xs,
  const float* __restrict__ pw1, const float* __restrict__ pb1,
  const float* __restrict__ pw2, const float* __restrict__ pb2,
  const float* __restrict__ pw3, const float* __restrict__ pb3,
  float* __restrict__ ws)
{
  __shared__ float s_w1[16*32], s_w2[32*64], s_w3[64*32];
  __shared__ float s_b1[32], s_b2[64], s_b3[32];
  __shared__ double red[256];
  const int tid = threadIdx.x;
  double* acc = (double*)ws;
  const float* ws_zs = ws + WS_ZS_OFF;

  for (int idx = tid; idx < 512; idx += 256) s_w1[idx] = pw1[idx];
  for (int idx = tid; idx < 2048; idx += 256){ s_w2[idx] = pw2[idx]; s_w3[idx] = pw3[idx]; }
  if (tid < 32) s_b1[tid] = pb1[tid];
  if (tid < 64) s_b2[tid] = pb2[tid];
  if (tid < 32) s_b3[tid] = pb3[tid];
  __syncthreads();

  size_t row = (size_t)blockIdx.x*256 + tid;   // row = t*2048 + b
  int t = (int)(row >> 11), b = (int)(row & 2047);
  float z[16];
  #pragma unroll
  for (int l = 0; l < 16; ++l) z[l] = ws_zs[row*16 + l];
  float h1[32];
  #pragma unroll
  for (int c = 0; c < 32; ++c){
    float s = s_b1[c];
    #pragma unroll
    for (int l = 0; l < 16; ++l) s += z[l]*s_w1[l*32 + c];
    h1[c] = tanhf(s);
  }
  float h2[64];
  #pragma unroll
  for (int c = 0; c < 64; ++c){
    float s = s_b2[c];
    #pragma unroll
    for (int k = 0; k < 32; ++k) s += h1[k]*s_w2[k*64 + c];
    h2[c] = tanhf(s);
  }
  double lp = 0.0;
  const float* xp = xs + ((size_t)b*TT + t)*DD;
  #pragma unroll
  for (int d = 0; d < 32; ++d){
    float s = s_b3[d];
    #pragma unroll
    for (int k = 0; k < 64; ++k) s += h2[k]*s_w3[k*32 + d];
    float diff = (xp[d] - s)*10.f;
    lp += (double)(-0.5f*diff*diff + 1.3836465597893728f);
  }
  red[tid] = lp;
  __syncthreads();
  if (tid == 0){ double s = 0; for (int i = 0; i < 256; ++i) s += red[i]; atomicAdd(&acc[0], s); }
}

__global__ void fin_kernel(const float* __restrict__ ws, float* __restrict__ out){
  const double* acc = (const double*)ws;
  out[0] = (float)(acc[0]/2048.0);
  out[1] = (float)(acc[1]/16.0 + acc[2]/255.0);
}

extern "C" void kernel_launch(void* const* d_in, const int* in_sizes, int n_in,
                              void* d_out, int out_size, void* d_ws, size_t ws_size,
                              hipStream_t stream)
{
  const float* xs        = (const float*)d_in[0];
  const float* ts        = (const float*)d_in[1];
  const float* act       = (const float*)d_in[2];
  const float* eps_z0    = (const float*)d_in[3];
  const float* dW        = (const float*)d_in[4];
  const float* gru_wih   = (const float*)d_in[5];
  const float* gru_whh   = (const float*)d_in[6];
  const float* gru_bih   = (const float*)d_in[7];
  const float* gru_bhh   = (const float*)d_in[8];
  const float* enc_w     = (const float*)d_in[9];
  const float* enc_b     = (const float*)d_in[10];
  const float* qz0_w     = (const float*)d_in[11];
  const float* qz0_b     = (const float*)d_in[12];
  const float* prior_w1  = (const float*)d_in[13];
  const float* prior_b1  = (const float*)d_in[14];
  const float* prior_w2  = (const float*)d_in[15];
  const float* prior_b2  = (const float*)d_in[16];
  const float* post_w1   = (const float*)d_in[17];
  const float* post_b1   = (const float*)d_in[18];
  const float* post_w2   = (const float*)d_in[19];
  const float* post_b2   = (const float*)d_in[20];
  const float* g_w1      = (const float*)d_in[21];
  const float* g_b1      = (const float*)d_in[22];
  const float* g_w2      = (const float*)d_in[23];
  const float* g_b2      = (const float*)d_in[24];
  const float* pw1       = (const float*)d_in[25];
  const float* pb1       = (const float*)d_in[26];
  const float* pw2       = (const float*)d_in[27];
  const float* pb2       = (const float*)d_in[28];
  const float* pw3       = (const float*)d_in[29];
  const float* pb3       = (const float*)d_in[30];
  const float* pz0_mean  = (const float*)d_in[31];
  const float* pz0_logstd= (const float*)d_in[32];
  float* ws = (float*)d_ws;

  hipMemsetAsync(d_ws, 0, 64, stream);
  init_kernel<<<1, 256, 0, stream>>>(post_w1, prior_w1, ws);
  gru_kernel<<<NBLK, 384, 0, stream>>>(xs, gru_wih, gru_whh, gru_bih, gru_bhh,
                                       enc_w, enc_b, qz0_w, qz0_b, eps_z0, pz0_mean, pz0_logstd, ws);
  int sde_lds = S_TOTAL*4;
  hipFuncSetAttribute(reinterpret_cast<const void*>(sde_kernel),
                      hipFuncAttributeMaxDynamicSharedMemorySize, sde_lds);
  sde_kernel<<<NBLK, 512, sde_lds, stream>>>(ts, act, dW,
                                             prior_b1, prior_w2, prior_b2,
                                             post_b1, post_w2, post_b2,
                                             g_w1, g_b1, g_w2, g_b2, ws);
  proj_kernel<<<(TT*BATCH)/256, 256, 0, stream>>>(xs, pw1, pb1, pw2, pb2, pw3, pb3, ws);
  fin_kernel<<<1, 1, 0, stream>>>(ws, (float*)d_out);
}

// Round 4
// 8826.760 us; speedup vs baseline: 4.6445x; 1.5296x over previous
//
#include <hip/hip_runtime.h>
#include <math.h>

#define BATCH 2048
#define TT 256
#define DD 32
#define LL 16
#define AA 8
#define CC 64
#define HH 128
#define G3 384
#define BB 8
#define NBLK (BATCH/BB)

// ---- workspace layout (float offsets) ----
// bytes [0,64): doubles acc[0]=lp, acc[1]=kl, acc[2]=lr
#define WS_W1T_OFF   1024                    // post_w1T [128][80]
#define WS_W1TP_OFF  11264                   // prior_w1T [128][16]
#define WS_ZS_OFF    16384                   // zs [256][2048][16]
#define WS_CTX_OFF   (WS_ZS_OFF + TT*BATCH*LL)  // ctx [256][2048][64]

__device__ __forceinline__ float dot4(float4 a, float4 b){
  return a.x*b.x + a.y*b.y + a.z*b.z + a.w*b.w;
}
// fast transcendentals (v_exp_f32 / v_log_f32 / rcp): ~1-2 ULP, vs 20-60-inst libm
__device__ __forceinline__ float softplusf_(float x){
  return fmaxf(x, 0.f) + __logf(1.f + __expf(-fabsf(x)));
}
__device__ __forceinline__ float sigmoidf_(float x){
  return __fdividef(1.f, 1.f + __expf(-x));
}
__device__ __forceinline__ float tanh_fast(float x){
  float e = __expf(-2.f*fabsf(x));
  float t = __fdividef(1.f - e, 1.f + e);
  return copysignf(t, x);
}

// ---- init: transpose post_w1 (80x128) and prior_w1 (16x128) into ws
__global__ void init_kernel(const float* __restrict__ post_w1, const float* __restrict__ prior_w1,
                            float* __restrict__ ws){
  int tid = threadIdx.x;
  float* w1T = ws + WS_W1T_OFF;
  for (int idx = tid; idx < 80*128; idx += 256){ int k = idx >> 7, n = idx & 127; w1T[n*80 + k] = post_w1[idx]; }
  float* w1Tp = ws + WS_W1TP_OFF;
  for (int idx = tid; idx < 16*128; idx += 256){ int k = idx >> 7, n = idx & 127; w1Tp[n*16 + k] = prior_w1[idx]; }
}

// ---- GRU (backward over time) + ctx + z0(->zs[0]) + KL ----
// 768 threads: split-K (s=tid&1 handles half of the whh/wih K-range), shfl-combine.
__global__ __launch_bounds__(768) void gru_kernel(
  const float* __restrict__ xs, const float* __restrict__ wih, const float* __restrict__ whh,
  const float* __restrict__ bih, const float* __restrict__ bhh,
  const float* __restrict__ enc_w, const float* __restrict__ enc_b,
  const float* __restrict__ qz0_w, const float* __restrict__ qz0_b,
  const float* __restrict__ eps_z0, const float* __restrict__ pz0_mean, const float* __restrict__ pz0_logstd,
  float* __restrict__ ws)
{
  __shared__ float h_lds[BB][HH];      // 4KB
  __shared__ float x_lds[BB][DD];      // 1KB
  __shared__ float encw[HH*CC];        // 32KB natural [j][c] (column reads: 2-way, free)
  __shared__ float scratch[2*G3*9];    // 27KB: gi | gh at stride 9
  float* gi = scratch;
  float* gh = scratch + G3*9;

  const int tid = threadIdx.x;
  const int b0  = blockIdx.x * BB;
  double* acc   = (double*)ws;
  float* ws_zs  = ws + WS_ZS_OFF;
  float* ws_ctx = ws + WS_CTX_OFF;

  for (int idx = tid; idx < HH*CC; idx += 768) encw[idx] = enc_w[idx];
  for (int idx = tid; idx < BB*HH; idx += 768) ((float*)h_lds)[idx] = 0.f;

  const int n = tid >> 1, s = tid & 1;
  const float bi0 = bih[n], bh0 = bhh[n];
  const float4* wi4 = (const float4*)(wih + (size_t)n*DD + 16*s);
  const float4* wh4 = (const float4*)(whh + (size_t)n*HH + 64*s);
  double klacc = 0.0;
  __syncthreads();

  for (int t = TT-1; t >= 0; --t){
    if (tid < BB*DD){ int r = tid >> 5, d = tid & 31; x_lds[r][d] = xs[((size_t)(b0+r)*TT + t)*DD + d]; }
    __syncthreads();
    // B: half-K GEMM, shfl-combine across s-pairs
    {
      float ai[BB], ah[BB];
      #pragma unroll
      for (int r = 0; r < BB; ++r){ ai[r] = 0.f; ah[r] = 0.f; }
      #pragma unroll
      for (int kq = 0; kq < 4; ++kq){
        float4 w = wi4[kq];
        #pragma unroll
        for (int r = 0; r < BB; ++r) ai[r] += dot4(w, *(const float4*)&x_lds[r][s*16 + kq*4]);
      }
      #pragma unroll 4
      for (int kq = 0; kq < 16; ++kq){
        float4 w = wh4[kq];
        #pragma unroll
        for (int r = 0; r < BB; ++r) ah[r] += dot4(w, *(const float4*)&h_lds[r][s*64 + kq*4]);
      }
      #pragma unroll
      for (int r = 0; r < BB; ++r){
        float aa = ai[r] + __shfl_xor(ai[r], 1);
        float hh = ah[r] + __shfl_xor(ah[r], 1);
        if (s == 0){ gi[n*9 + r] = aa + bi0; gh[n*9 + r] = hh + bh0; }
      }
    }
    __syncthreads();
    // C: gates + h update
    for (int idx = tid; idx < HH*BB; idx += 768){
      int j = idx & (HH-1); int r = idx >> 7;
      float rg = sigmoidf_(gi[j*9 + r] + gh[j*9 + r]);
      float zg = sigmoidf_(gi[(j+HH)*9 + r] + gh[(j+HH)*9 + r]);
      float ng = tanh_fast(gi[(j+2*HH)*9 + r] + rg*gh[(j+2*HH)*9 + r]);
      h_lds[r][j] = (1.f - zg)*ng + zg*h_lds[r][j];
    }
    __syncthreads();
    // D: ctx[t] = h@enc_w + enc_b  (h broadcast per wave; encw column reads 2-way)
    float* ctx0 = scratch;   // alias (gi dead after C)
    if (tid < CC*BB){
      int c = tid & 63, r = tid >> 6;
      float sum = enc_b[c];
      #pragma unroll 8
      for (int j = 0; j < HH; ++j) sum += encw[j*CC + c]*h_lds[r][j];
      ws_ctx[((size_t)t*BATCH + b0 + r)*CC + c] = sum;
      if (t == 0) ctx0[r*CC + c] = sum;
    }
    __syncthreads();
    if (t == 0){
      float* qmb = scratch + 512;
      float* qlb = scratch + 640;
      if (tid < 256){ int m = tid & 31, r = tid >> 5;
        float q = qz0_b[m];
        for (int c2 = 0; c2 < CC; ++c2) q += ctx0[r*CC + c2]*qz0_w[c2*32 + m];
        if (m < 16) qmb[r*16 + m] = q; else qlb[r*16 + (m-16)] = q;
      }
      __syncthreads();
      if (tid < BB*LL){
        int l = tid & 15, r = tid >> 4;
        float qm = qmb[r*16 + l], ql = qlb[r*16 + l];
        ws_zs[(size_t)(b0+r)*LL + l] = qm + expf(ql)*eps_z0[(size_t)(b0+r)*LL + l];
        float pm = pz0_mean[l], pl = pz0_logstd[l];
        float d  = qm - pm;
        klacc = (double)(pl - ql + (expf(2.f*ql) + d*d)/(2.f*expf(2.f*pl)) - 0.5f);
      }
      __syncthreads();
    }
  }
  double* redb = (double*)(scratch + 1024);
  redb[tid] = klacc;
  __syncthreads();
  if (tid == 0){ double sum = 0; for (int i = 0; i < 768; ++i) sum += redb[i]; atomicAdd(&acc[1], sum); }
}

// ---- SDE scan ----
// LDS float offsets (all regions 16B-aligned; padded strides kill bank conflicts)
#define S_W2P  0       /* [128][128] XOR-swizzled */
#define S_W2R  16384
#define S_ZIN  32768   /* [8][84]: 0..15 z, 16..79 ctx(t+1); 84%32=20 -> 8 distinct banks */
#define S_HDP  33440   /* [8][132]: 132%32=4 -> conflict-free row reads */
#define S_HDR  34496
#define S_MATP 35552   /* alias: RED (512 doubles) */
#define S_MATR 36608
#define S_G    37664   /* g0 [16][16] l*16+r ; g1 at +256 */
#define S_DWV  38176   /* [8][16] raw dW */
#define S_DXV  38304   /* [8][8] */
#define S_TS   38368   /* [256] */
#define S_TOTAL 38624  /* floats -> 154496 bytes */

__global__ __launch_bounds__(512) void sde_kernel(
  const float* __restrict__ ts, const float* __restrict__ act, const float* __restrict__ dW,
  const float* __restrict__ prior_b1, const float* __restrict__ prior_w2, const float* __restrict__ prior_b2,
  const float* __restrict__ post_b1,  const float* __restrict__ post_w2,  const float* __restrict__ post_b2,
  const float* __restrict__ g_w1, const float* __restrict__ g_b1, const float* __restrict__ g_w2, const float* __restrict__ g_b2,
  float* __restrict__ ws)
{
  extern __shared__ __align__(16) float sm[];
  const int tid = threadIdx.x;
  const int b0  = blockIdx.x * BB;
  double* acc = (double*)ws;
  const float* w1T    = ws + WS_W1T_OFF;
  const float* w1Tp   = ws + WS_W1TP_OFF;
  float*       ws_zs  = ws + WS_ZS_OFF;
  const float* ws_ctx = ws + WS_CTX_OFF;

  // stage w2 matrices, XOR-swizzled: [j][h ^ ((j&15)<<2)]
  for (int idx = tid; idx < HH*HH; idx += 512){
    int h = idx >> 7, j = idx & 127;
    int d = j*HH + (h ^ ((j&15)<<2));
    sm[S_W2P + d] = post_w2[idx];
    sm[S_W2R + d] = prior_w2[idx];
  }
  // per-thread register preloads (constant across all 255 steps)
  const int an = tid >> 2, aq = tid & 3;
  const float b1p = post_b1[an], b1r = prior_b1[an];
  const float b2p = post_b2[an], b2r = prior_b2[an];
  const float4 w1p0 = *(const float4*)(w1Tp + an*16);
  const float4 w1p1 = *(const float4*)(w1Tp + an*16 + 4);
  const float4 w1p2 = *(const float4*)(w1Tp + an*16 + 8);
  const float4 w1p3 = *(const float4*)(w1Tp + an*16 + 12);
  const int gl = tid >> 5, gii = tid & 31;
  const float4 gw1 = *(const float4*)&g_w1[gl*HH + gii*4];
  const float4 gb1 = *(const float4*)&g_b1[gl*HH + gii*4];
  const float4 gw2 = *(const float4*)&g_w2[gl*HH + gii*4];
  const float gb2 = g_b2[gl];

  if (tid < 256) sm[S_TS + tid] = ts[tid];
  if (tid < BB*LL){
    int r = tid >> 4, l = tid & 15;
    sm[S_ZIN + r*84 + l] = ws_zs[(size_t)(b0+r)*LL + l];
    sm[S_DWV + tid] = dW[(size_t)b0*LL + tid];          // t=0
  } else {
    for (int k = tid-128; k < BB*CC; k += 384){          // ctx[1]
      int r = k >> 6, c = k & 63;
      sm[S_ZIN + r*84 + 16 + c] = ws_ctx[((size_t)BATCH + b0 + r)*CC + c];
    }
    if (tid >= 448){ int k = tid-448; int r = k >> 3, a = k & 7;
      float dt0 = ts[1] - ts[0];
      size_t base = ((size_t)(b0+r)*TT)*AA + a;
      sm[S_DXV + k] = (act[base + AA] - act[base])/dt0;
    }
  }
  double lracc = 0.0;
  float fv_reg = 0.f, hv_reg = 0.f, dwv_reg = 0.f;
  __syncthreads();

  for (int t = 0; t < TT-1; ++t){
    const float dtk = sm[S_TS + t + 1] - sm[S_TS + t];
    const float sqd = sqrtf(dtk);

    // A: hdd_post = tanh([z|ctx]@post_w1+b1); hdd_prior = tanh(z@prior_w1+b1)
    {
      const float4* w4 = (const float4*)(w1T + an*80);
      float a0 = b1p, a1 = b1p;
      #pragma unroll 5
      for (int kq = 0; kq < 20; ++kq){
        float4 w = w4[kq];
        a0 += dot4(w, *(const float4*)&sm[S_ZIN + aq*84 + kq*4]);
        a1 += dot4(w, *(const float4*)&sm[S_ZIN + (aq+4)*84 + kq*4]);
      }
      sm[S_HDP + aq*132 + an]     = tanh_fast(a0);
      sm[S_HDP + (aq+4)*132 + an] = tanh_fast(a1);
      float c0 = b1r, c1 = b1r;
      c0 += dot4(w1p0, *(const float4*)&sm[S_ZIN + aq*84]);      c1 += dot4(w1p0, *(const float4*)&sm[S_ZIN + (aq+4)*84]);
      c0 += dot4(w1p1, *(const float4*)&sm[S_ZIN + aq*84 + 4]);  c1 += dot4(w1p1, *(const float4*)&sm[S_ZIN + (aq+4)*84 + 4]);
      c0 += dot4(w1p2, *(const float4*)&sm[S_ZIN + aq*84 + 8]);  c1 += dot4(w1p2, *(const float4*)&sm[S_ZIN + (aq+4)*84 + 8]);
      c0 += dot4(w1p3, *(const float4*)&sm[S_ZIN + aq*84 + 12]); c1 += dot4(w1p3, *(const float4*)&sm[S_ZIN + (aq+4)*84 + 12]);
      sm[S_HDR + aq*132 + an]     = tanh_fast(c0);
      sm[S_HDR + (aq+4)*132 + an] = tanh_fast(c1);
    }
    __syncthreads();
    // B: mat_post, mat_prior (w2 swizzled reads 2-way; hdd reads conflict-free at 132)
    {
      float mp0 = b2p, mp1 = b2p, mr0 = b2r, mr1 = b2r;
      #pragma unroll 4
      for (int kq = 0; kq < 32; ++kq){
        int wo = (kq*4) ^ ((an&15)<<2);
        float4 wp = *(const float4*)&sm[S_W2P + an*HH + wo];
        float4 wr = *(const float4*)&sm[S_W2R + an*HH + wo];
        float4 p0 = *(const float4*)&sm[S_HDP + aq*132 + kq*4];
        float4 p1 = *(const float4*)&sm[S_HDP + (aq+4)*132 + kq*4];
        float4 q0 = *(const float4*)&sm[S_HDR + aq*132 + kq*4];
        float4 q1 = *(const float4*)&sm[S_HDR + (aq+4)*132 + kq*4];
        mp0 += dot4(wp, p0); mp1 += dot4(wp, p1);
        mr0 += dot4(wr, q0); mr1 += dot4(wr, q1);
      }
      sm[S_MATP + aq*132 + an] = mp0; sm[S_MATP + (aq+4)*132 + an] = mp1;
      sm[S_MATR + aq*132 + an] = mr0; sm[S_MATR + (aq+4)*132 + an] = mr1;
    }
    __syncthreads();
    // C': g0+g1 fully in-register (shfl butterfly over 32-lane h-groups) + f/h einsum
    {
      float g0v[8], g1v[8], sacc[8];
      #pragma unroll
      for (int r = 0; r < 8; ++r){
        float z = sm[S_ZIN + r*84 + gl];
        sacc[r] = softplusf_(z*gw1.x + gb1.x)*gw2.x + softplusf_(z*gw1.y + gb1.y)*gw2.y
                + softplusf_(z*gw1.z + gb1.z)*gw2.z + softplusf_(z*gw1.w + gb1.w)*gw2.w;
      }
      #pragma unroll
      for (int r = 0; r < 8; ++r){
        float v = sacc[r];
        v += __shfl_xor(v, 1); v += __shfl_xor(v, 2); v += __shfl_xor(v, 4);
        v += __shfl_xor(v, 8); v += __shfl_xor(v, 16);
        g0v[r] = sigmoidf_(v + gb2);
      }
      #pragma unroll
      for (int r = 0; r < 8; ++r){
        float z2 = sm[S_ZIN + r*84 + gl] + g0v[r]*(sm[S_DWV + r*16 + gl]*sqd);
        sacc[r] = softplusf_(z2*gw1.x + gb1.x)*gw2.x + softplusf_(z2*gw1.y + gb1.y)*gw2.y
                + softplusf_(z2*gw1.z + gb1.z)*gw2.z + softplusf_(z2*gw1.w + gb1.w)*gw2.w;
      }
      #pragma unroll
      for (int r = 0; r < 8; ++r){
        float v = sacc[r];
        v += __shfl_xor(v, 1); v += __shfl_xor(v, 2); v += __shfl_xor(v, 4);
        v += __shfl_xor(v, 8); v += __shfl_xor(v, 16);
        g1v[r] = sigmoidf_(v + gb2);
      }
      if (gii == 0){
        #pragma unroll
        for (int r = 0; r < 8; ++r){
          sm[S_G + gl*16 + r]       = g0v[r];
          sm[S_G + 256 + gl*16 + r] = g1v[r];
        }
      }
      if (tid < BB*LL){
        const int r = tid >> 4, l = tid & 15;
        float4 dxa = *(const float4*)&sm[S_DXV + r*8];
        float4 dxb = *(const float4*)&sm[S_DXV + r*8 + 4];
        float4 mpa = *(const float4*)&sm[S_MATP + r*132 + l*8];
        float4 mpb = *(const float4*)&sm[S_MATP + r*132 + l*8 + 4];
        float4 mra = *(const float4*)&sm[S_MATR + r*132 + l*8];
        float4 mrb = *(const float4*)&sm[S_MATR + r*132 + l*8 + 4];
        fv_reg = dot4(mpa, dxa) + dot4(mpb, dxb);
        hv_reg = dot4(mra, dxa) + dot4(mrb, dxb);
        dwv_reg = sm[S_DWV + tid]*sqd;
      }
    }
    __syncthreads();
    // F: state update + lr (tid<128)  ||  prefetch next-step ctx/dW/dxdt (others)
    if (tid < BB*LL){
      const int r = tid >> 4, l = tid & 15;
      float g0 = sm[S_G + l*16 + r];
      float g1 = sm[S_G + 256 + l*16 + r];
      float zc = sm[S_ZIN + r*84 + l];
      float zn = zc + fv_reg*dtk + 0.5f*(g0 + g1)*dwv_reg;
      float u  = (fv_reg - hv_reg)/g0;
      lracc += (double)(0.5f*u*u*dtk);
      sm[S_ZIN + r*84 + l] = zn;
      ws_zs[((size_t)(t+1)*BATCH + b0 + r)*LL + l] = zn;
    } else if (t < TT-2){
      for (int k = tid-128; k < BB*CC; k += 384){
        int r = k >> 6, c = k & 63;
        sm[S_ZIN + r*84 + 16 + c] = ws_ctx[((size_t)(t+2)*BATCH + b0 + r)*CC + c];
      }
      if (tid < 256) sm[S_DWV + (tid-128)] = dW[(size_t)(t+1)*BATCH*LL + (size_t)b0*LL + (tid-128)];
      if (tid >= 448){ int k = tid-448; int r = k >> 3, a = k & 7;
        float dtn = sm[S_TS + t + 2] - sm[S_TS + t + 1];
        size_t base = ((size_t)(b0+r)*TT + (t+1))*AA + a;
        sm[S_DXV + k] = (act[base + AA] - act[base])/dtn;
      }
    }
    __syncthreads();
  }

  // lr reduction (alias MATP region for 512 doubles)
  double* redb = (double*)&sm[S_MATP];
  redb[tid] = lracc;
  __syncthreads();
  if (tid == 0){ double sum = 0; for (int i = 0; i < 512; ++i) sum += redb[i]; atomicAdd(&acc[2], sum); }
}

// ---- fully parallel projection + log-likelihood over all (t,b) ----
__global__ __launch_bounds__(256) void proj_kernel(
  const float* __restrict__ xs,
  const float* __restrict__ pw1, const float* __restrict__ pb1,
  const float* __restrict__ pw2, const float* __restrict__ pb2,
  const float* __restrict__ pw3, const float* __restrict__ pb3,
  float* __restrict__ ws)
{
  __shared__ float s_w1[16*32], s_w2[32*64], s_w3[64*32];
  __shared__ float s_b1[32], s_b2[64], s_b3[32];
  __shared__ double red[256];
  const int tid = threadIdx.x;
  double* acc = (double*)ws;
  const float* ws_zs = ws + WS_ZS_OFF;

  for (int idx = tid; idx < 512; idx += 256) s_w1[idx] = pw1[idx];
  for (int idx = tid; idx < 2048; idx += 256){ s_w2[idx] = pw2[idx]; s_w3[idx] = pw3[idx]; }
  if (tid < 32) s_b1[tid] = pb1[tid];
  if (tid < 64) s_b2[tid] = pb2[tid];
  if (tid < 32) s_b3[tid] = pb3[tid];
  __syncthreads();

  size_t row = (size_t)blockIdx.x*256 + tid;   // row = t*2048 + b
  int t = (int)(row >> 11), b = (int)(row & 2047);
  float z[16];
  #pragma unroll
  for (int l = 0; l < 16; ++l) z[l] = ws_zs[row*16 + l];
  float h1[32];
  #pragma unroll
  for (int c = 0; c < 32; ++c){
    float s = s_b1[c];
    #pragma unroll
    for (int l = 0; l < 16; ++l) s += z[l]*s_w1[l*32 + c];
    h1[c] = tanh_fast(s);
  }
  float h2[64];
  #pragma unroll
  for (int c = 0; c < 64; ++c){
    float s = s_b2[c];
    #pragma unroll
    for (int k = 0; k < 32; ++k) s += h1[k]*s_w2[k*64 + c];
    h2[c] = tanh_fast(s);
  }
  double lp = 0.0;
  const float* xp = xs + ((size_t)b*TT + t)*DD;
  #pragma unroll
  for (int d = 0; d < 32; ++d){
    float s = s_b3[d];
    #pragma unroll
    for (int k = 0; k < 64; ++k) s += h2[k]*s_w3[k*32 + d];
    float diff = (xp[d] - s)*10.f;
    lp += (double)(-0.5f*diff*diff + 1.3836465597893728f);
  }
  red[tid] = lp;
  __syncthreads();
  if (tid == 0){ double s = 0; for (int i = 0; i < 256; ++i) s += red[i]; atomicAdd(&acc[0], s); }
}

__global__ void fin_kernel(const float* __restrict__ ws, float* __restrict__ out){
  const double* acc = (const double*)ws;
  out[0] = (float)(acc[0]/2048.0);
  out[1] = (float)(acc[1]/16.0 + acc[2]/255.0);
}

extern "C" void kernel_launch(void* const* d_in, const int* in_sizes, int n_in,
                              void* d_out, int out_size, void* d_ws, size_t ws_size,
                              hipStream_t stream)
{
  const float* xs        = (const float*)d_in[0];
  const float* ts        = (const float*)d_in[1];
  const float* act       = (const float*)d_in[2];
  const float* eps_z0    = (const float*)d_in[3];
  const float* dW        = (const float*)d_in[4];
  const float* gru_wih   = (const float*)d_in[5];
  const float* gru_whh   = (const float*)d_in[6];
  const float* gru_bih   = (const float*)d_in[7];
  const float* gru_bhh   = (const float*)d_in[8];
  const float* enc_w     = (const float*)d_in[9];
  const float* enc_b     = (const float*)d_in[10];
  const float* qz0_w     = (const float*)d_in[11];
  const float* qz0_b     = (const float*)d_in[12];
  const float* prior_w1  = (const float*)d_in[13];
  const float* prior_b1  = (const float*)d_in[14];
  const float* prior_w2  = (const float*)d_in[15];
  const float* prior_b2  = (const float*)d_in[16];
  const float* post_w1   = (const float*)d_in[17];
  const float* post_b1   = (const float*)d_in[18];
  const float* post_w2   = (const float*)d_in[19];
  const float* post_b2   = (const float*)d_in[20];
  const float* g_w1      = (const float*)d_in[21];
  const float* g_b1      = (const float*)d_in[22];
  const float* g_w2      = (const float*)d_in[23];
  const float* g_b2      = (const float*)d_in[24];
  const float* pw1       = (const float*)d_in[25];
  const float* pb1       = (const float*)d_in[26];
  const float* pw2       = (const float*)d_in[27];
  const float* pb2       = (const float*)d_in[28];
  const float* pw3       = (const float*)d_in[29];
  const float* pb3       = (const float*)d_in[30];
  const float* pz0_mean  = (const float*)d_in[31];
  const float* pz0_logstd= (const float*)d_in[32];
  float* ws = (float*)d_ws;

  hipMemsetAsync(d_ws, 0, 64, stream);
  init_kernel<<<1, 256, 0, stream>>>(post_w1, prior_w1, ws);
  gru_kernel<<<NBLK, 768, 0, stream>>>(xs, gru_wih, gru_whh, gru_bih, gru_bhh,
                                       enc_w, enc_b, qz0_w, qz0_b, eps_z0, pz0_mean, pz0_logstd, ws);
  int sde_lds = S_TOTAL*4;
  hipFuncSetAttribute(reinterpret_cast<const void*>(sde_kernel),
                      hipFuncAttributeMaxDynamicSharedMemorySize, sde_lds);
  sde_kernel<<<NBLK, 512, sde_lds, stream>>>(ts, act, dW,
                                             prior_b1, prior_w2, prior_b2,
                                             post_b1, post_w2, post_b2,
                                             g_w1, g_b1, g_w2, g_b2, ws);
  proj_kernel<<<(TT*BATCH)/256, 256, 0, stream>>>(xs, pw1, pb1, pw2, pb2, pw3, pb3, ws);
  fin_kernel<<<1, 1, 0, stream>>>(ws, (float*)d_out);
}